// Round 1
// baseline (771.571 us; speedup 1.0000x reference)
//
#include <hip/hip_runtime.h>
#include <math.h>

// Problem constants (fixed by setup_inputs)
#define M 8192
#define N 256
#define K 7168
#define N_GROUPS 8
#define TOPK 8
#define ROUTE_SCALE 2.5f

// GEMM tiling
#define BM 64
#define BN 64
#define BK 16

// ---------------------------------------------------------------------------
// Kernel 1: S[m][n] = sigmoid(x[m][:] . W[n][:] + bias[n])
// Both operands are K-major (row-major A [M,K], row-major W [N,K]) -> "NT" GEMM.
// LDS tiles stored transposed [k][m] (pad +4 floats keeps 16B alignment and
// only 2-way bank aliasing, which is free on CDNA4).
// ---------------------------------------------------------------------------
__global__ __launch_bounds__(256) void gemm_sigmoid(
        const float* __restrict__ A,     // [M,K] x
        const float* __restrict__ B,     // [N,K] weight
        const float* __restrict__ bias,  // [N]
        float* __restrict__ S) {         // [M,N] scores
    __shared__ __align__(16) float As[BK][BM + 4];
    __shared__ __align__(16) float Bs[BK][BN + 4];

    const int tid = threadIdx.x;
    const int n0 = blockIdx.x * BN;
    const int m0 = blockIdx.y * BM;
    const int tx = tid & 15;          // n-dim thread coord (0..15)
    const int ty = tid >> 4;          // m-dim thread coord (0..15)
    const int lr = tid >> 2;          // staging row within tile (0..63)
    const int lk = (tid & 3) << 2;    // staging k offset {0,4,8,12}

    float acc[4][4] = {};

    const float* Ap = A + (long)(m0 + lr) * K + lk;
    const float* Bp = B + (long)(n0 + lr) * K + lk;

    for (int k0 = 0; k0 < K; k0 += BK) {
        float4 a4 = *reinterpret_cast<const float4*>(Ap + k0);
        float4 b4 = *reinterpret_cast<const float4*>(Bp + k0);
        __syncthreads();  // previous tile's readers must be done
        As[lk + 0][lr] = a4.x; As[lk + 1][lr] = a4.y;
        As[lk + 2][lr] = a4.z; As[lk + 3][lr] = a4.w;
        Bs[lk + 0][lr] = b4.x; Bs[lk + 1][lr] = b4.y;
        Bs[lk + 2][lr] = b4.z; Bs[lk + 3][lr] = b4.w;
        __syncthreads();
#pragma unroll
        for (int k = 0; k < BK; ++k) {
            float4 av = *reinterpret_cast<const float4*>(&As[k][ty * 4]);
            float4 bv = *reinterpret_cast<const float4*>(&Bs[k][tx * 4]);
            const float am[4] = {av.x, av.y, av.z, av.w};
            const float bn_[4] = {bv.x, bv.y, bv.z, bv.w};
#pragma unroll
            for (int i = 0; i < 4; ++i)
#pragma unroll
                for (int j = 0; j < 4; ++j)
                    acc[i][j] = fmaf(am[i], bn_[j], acc[i][j]);
        }
    }

    // Epilogue: + bias, sigmoid, store
    const int gm = m0 + ty * 4;
    const int gn = n0 + tx * 4;
    const float4 bb = *reinterpret_cast<const float4*>(bias + gn);
    const float bvv[4] = {bb.x, bb.y, bb.z, bb.w};
#pragma unroll
    for (int i = 0; i < 4; ++i) {
        float4 o;
        o.x = 1.f / (1.f + expf(-(acc[i][0] + bvv[0])));
        o.y = 1.f / (1.f + expf(-(acc[i][1] + bvv[1])));
        o.z = 1.f / (1.f + expf(-(acc[i][2] + bvv[2])));
        o.w = 1.f / (1.f + expf(-(acc[i][3] + bvv[3])));
        *reinterpret_cast<float4*>(S + (long)(gm + i) * N + gn) = o;
    }
}

// ---------------------------------------------------------------------------
// Kernel 2: group-limited top-k gating. One wave (64 lanes) per row.
// Lane l owns experts 4l..4l+3 (group g = experts 32g..32g+31 = lanes 8g..8g+7).
// Tie-breaking everywhere: equal value -> lower index wins (jax.lax.top_k is
// stable / returns lowest index first).
// ---------------------------------------------------------------------------
__global__ __launch_bounds__(256) void gate_topk(
        const float* __restrict__ S,   // [M,N] sigmoid scores
        float* __restrict__ out_w,     // [M,TOPK]
        float* __restrict__ out_i) {   // [M,TOPK] indices stored as float
    const int row = blockIdx.x * 4 + (threadIdx.x >> 6);
    const int lane = threadIdx.x & 63;

    const float4 s4 = *reinterpret_cast<const float4*>(S + (long)row * N + lane * 4);
    float v[4] = {s4.x, s4.y, s4.z, s4.w};

    // ---- per-lane top-2 of its 4 scores (values only; used for group score)
    float t1 = v[0], t2 = -1.f;
#pragma unroll
    for (int j = 1; j < 4; ++j) {
        if (v[j] > t1) { t2 = t1; t1 = v[j]; }
        else if (v[j] > t2) { t2 = v[j]; }
    }
    // ---- merge top-2 across the 8 lanes of the group
#pragma unroll
    for (int m = 1; m <= 4; m <<= 1) {
        const float o1 = __shfl_xor(t1, m, 64);
        const float o2 = __shfl_xor(t2, m, 64);
        const float n1 = fmaxf(t1, o1);
        const float n2 = fmaxf(fminf(t1, o1), fmaxf(t2, o2));
        t1 = n1; t2 = n2;
    }
    float gs = t1 + t2;       // group score (same in all 8 lanes of the group)
    int gid = lane >> 3;
    // ---- argmax over the 8 groups (stable: lower group index on tie)
#pragma unroll
    for (int m = 8; m <= 32; m <<= 1) {
        const float og = __shfl_xor(gs, m, 64);
        const int oi = __shfl_xor(gid, m, 64);
        if (og > gs || (og == gs && oi < gid)) { gs = og; gid = oi; }
    }
    // gid now = selected group on every lane

    // ---- top-8 among the 32 scores of the selected group
    const bool inG = ((lane >> 3) == gid);
    if (!inG) { v[0] = v[1] = v[2] = v[3] = -1.f; }  // scores are in (0,1)

    float wv[8];
    int wi[8];
#pragma unroll
    for (int r = 0; r < 8; ++r) {
        // local best of remaining (strict > keeps lower j on ties)
        float bv = v[0]; int bj = 0;
#pragma unroll
        for (int j = 1; j < 4; ++j)
            if (v[j] > bv) { bv = v[j]; bj = j; }
        int be = lane * 4 + bj;
        // wave-wide argmax, stable
#pragma unroll
        for (int m = 1; m <= 32; m <<= 1) {
            const float ov = __shfl_xor(bv, m, 64);
            const int oe = __shfl_xor(be, m, 64);
            if (ov > bv || (ov == bv && oe < be)) { bv = ov; be = oe; }
        }
        wv[r] = bv; wi[r] = be;
        if ((be >> 2) == lane) v[be & 3] = -1.f;  // owner removes the winner
    }

    float sum = 0.f;
#pragma unroll
    for (int r = 0; r < 8; ++r) sum += wv[r];

    if (lane == 0) {
#pragma unroll
        for (int r = 0; r < 8; ++r) {
            out_w[(long)row * TOPK + r] = wv[r] / sum * ROUTE_SCALE;
            out_i[(long)row * TOPK + r] = (float)wi[r];
        }
    }
}

// ---------------------------------------------------------------------------
extern "C" void kernel_launch(void* const* d_in, const int* in_sizes, int n_in,
                              void* d_out, int out_size, void* d_ws, size_t ws_size,
                              hipStream_t stream) {
    const float* x = (const float*)d_in[0];      // [M,K]
    const float* w = (const float*)d_in[1];      // [N,K]
    const float* b = (const float*)d_in[2];      // [N]
    float* scores = (float*)d_ws;                // [M,N] scratch (8 MB)
    float* out_w = (float*)d_out;                // [M,TOPK]
    float* out_i = out_w + (long)M * TOPK;       // [M,TOPK] as float

    dim3 ggrid(N / BN, M / BM);  // (4, 128) -> 512 blocks, 2/CU, co-resident
    gemm_sigmoid<<<ggrid, 256, 0, stream>>>(x, w, b, scores);

    gate_topk<<<M / 4, 256, 0, stream>>>(scores, out_w, out_i);
}

// Round 2
// 401.436 us; speedup vs baseline: 1.9220x; 1.9220x over previous
//
#include <hip/hip_runtime.h>
#include <math.h>

// Problem constants (fixed by setup_inputs)
#define M 8192
#define N 256
#define K 7168
#define KH 3584            // K/2 (K-split factor 2)
#define N_GROUPS 8
#define TOPK 8
#define ROUTE_SCALE 2.5f

// GEMM tiling
#define BM 64
#define BN 128
#define BK 64

typedef _Float16 half8 __attribute__((ext_vector_type(8)));
typedef _Float16 half4 __attribute__((ext_vector_type(4)));
typedef float f32x4 __attribute__((ext_vector_type(4)));

// global -> LDS direct copy, 16B per lane; LDS dest = wave-uniform base + lane*16
__device__ __forceinline__ void gload_lds16(const void* g, void* l) {
    __builtin_amdgcn_global_load_lds(
        (const __attribute__((address_space(1))) unsigned int*)g,
        (__attribute__((address_space(3))) unsigned int*)l,
        16, 0, 0);
}

// ---------------------------------------------------------------------------
// Kernel 0: split W (fp32) into fp16 hi + fp16 residual lo. 7.3 MB, ~4 us.
// ---------------------------------------------------------------------------
__global__ __launch_bounds__(256) void convert_w(
        const float* __restrict__ W, _Float16* __restrict__ Wh,
        _Float16* __restrict__ Wl) {
    const int idx = blockIdx.x * 256 + threadIdx.x;   // float4 index
    const float4 w = ((const float4*)W)[idx];
    const float e[4] = {w.x, w.y, w.z, w.w};
    half4 h, l;
#pragma unroll
    for (int j = 0; j < 4; ++j) {
        const _Float16 hv = (_Float16)e[j];
        h[j] = hv;
        l[j] = (_Float16)(e[j] - (float)hv);
    }
    ((half4*)Wh)[idx] = h;
    ((half4*)Wl)[idx] = l;
}

// ---------------------------------------------------------------------------
// Kernel 1: partial logits P[ks][m][n] = sum_{k in half ks} x[m,k]*W[n,k]
// via 3-term fp16 split MFMA: xh*wh + xh*wl + xl*wh  (~1e-7 of fp32).
// LDS tiles [rows][64 f16], 16B-chunk c of row r stored at chunk c^(r&7)
// (XOR swizzle, both write and read sides).
// ---------------------------------------------------------------------------
__global__ __launch_bounds__(256, 2) void gemm_split(
        const float* __restrict__ X,      // [M,K] fp32
        const _Float16* __restrict__ Wh,  // [N,K] f16 hi
        const _Float16* __restrict__ Wl,  // [N,K] f16 lo
        float* __restrict__ P0,           // [M,N] partial (K-half 0)
        float* __restrict__ P1) {         // [M,N] partial (K-half 1)
    __shared__ _Float16 Ah[BM][BK], Al[BM][BK];   // 8 KB each
    __shared__ _Float16 Bh[BN][BK], Bl[BN][BK];   // 16 KB each -> 48 KB total

    const int tid = threadIdx.x;
    const int bid = blockIdx.x;
    // XCD-aware decode: dispatch round-robins XCD = bid&7. Blocks sharing the
    // same W quadrant (nb,ks) land on one XCD pair -> W tile stays L2-resident.
    const int xs = bid & 7;
    const int q = xs >> 1;                 // quadrant 0..3
    const int nb = q & 1, ks = q >> 1;
    const int mb = ((bid >> 3) << 1) | (xs & 1);   // 0..127
    const int m0 = mb * BM, n0 = nb * BN, kb = ks * KH;

    const int lane = tid & 63, wave = tid >> 6;
    const int wr = wave >> 1, wc = wave & 1;       // wave grid 2x2
    const int lrow = lane & 15, lkq = lane >> 4;   // fragment coords

    // B staging (global_load_lds): wave-issue covers 8 rows (64 lanes x 16B)
    const int blr = lane >> 3;                 // row within 8-row chunk
    const int bcsw = (lane & 7) ^ blr;         // pre-swizzled source chunk

    // A staging (reg: fp32 -> f16 hi/lo): thread owns row ar, chunks ac0,ac0+1
    const int ar = tid >> 2;
    const int ac0 = (tid & 3) << 1;

    f32x4 acc[2][4];
#pragma unroll
    for (int i = 0; i < 2; ++i)
#pragma unroll
        for (int j = 0; j < 4; ++j) acc[i][j] = (f32x4){0.f, 0.f, 0.f, 0.f};

    const float* Abase = X + (size_t)(m0 + ar) * K + kb + ac0 * 8;
    const _Float16* Whb = Wh + kb + bcsw * 8;
    const _Float16* Wlb = Wl + kb + bcsw * 8;

    for (int k0 = 0; k0 < KH; k0 += BK) {
        __syncthreads();   // previous iteration's readers done
        // ---- B: 4 issues/wave for hi and lo (16B/lane, linear LDS dest,
        //      swizzle achieved by pre-swizzled global source chunk)
#pragma unroll
        for (int i = 0; i < 4; ++i) {
            const int r8 = wave * 4 + i;           // 8-row chunk 0..15
            const int lr = r8 * 8 + blr;           // 0..127
            const size_t go = (size_t)(n0 + lr) * K + k0;
            gload_lds16(Whb + go, &Bh[r8 * 8][0]);
            gload_lds16(Wlb + go, &Bl[r8 * 8][0]);
        }
        // ---- A: 16 fp32 -> 2x(8 f16 hi + 8 f16 lo), swizzled ds_write_b128
        const float* ga = Abase + k0;
        float4 f[4];
#pragma unroll
        for (int i = 0; i < 4; ++i) f[i] = ((const float4*)ga)[i];
#pragma unroll
        for (int c = 0; c < 2; ++c) {
            const float e[8] = {f[c*2].x, f[c*2].y, f[c*2].z, f[c*2].w,
                                f[c*2+1].x, f[c*2+1].y, f[c*2+1].z, f[c*2+1].w};
            half8 h, l;
#pragma unroll
            for (int j = 0; j < 8; ++j) {
                const _Float16 hv = (_Float16)e[j];
                h[j] = hv;
                l[j] = (_Float16)(e[j] - (float)hv);
            }
            const int p = (ac0 + c) ^ (ar & 7);
            *(half8*)&Ah[ar][p * 8] = h;
            *(half8*)&Al[ar][p * 8] = l;
        }
        __syncthreads();   // drains global_load_lds (vmcnt) + ds_write (lgkm)

        // ---- compute: per wave 48 MFMA, 24 ds_read_b128 per K-step
#pragma unroll
        for (int s = 0; s < 2; ++s) {
            const int pc8 = ((s * 4 + lkq) ^ (lrow & 7)) * 8;  // swizzled chunk
            const half8 ah0 = *(const half8*)&Ah[wr*32 + lrow][pc8];
            const half8 ah1 = *(const half8*)&Ah[wr*32 + 16 + lrow][pc8];
            const half8 al0 = *(const half8*)&Al[wr*32 + lrow][pc8];
            const half8 al1 = *(const half8*)&Al[wr*32 + 16 + lrow][pc8];
#pragma unroll
            for (int j = 0; j < 4; ++j) {
                const int br = wc*64 + j*16 + lrow;
                const half8 bh = *(const half8*)&Bh[br][pc8];
                const half8 bl = *(const half8*)&Bl[br][pc8];
                acc[0][j] = __builtin_amdgcn_mfma_f32_16x16x32_f16(ah0, bh, acc[0][j], 0, 0, 0);
                acc[1][j] = __builtin_amdgcn_mfma_f32_16x16x32_f16(ah1, bh, acc[1][j], 0, 0, 0);
                acc[0][j] = __builtin_amdgcn_mfma_f32_16x16x32_f16(ah0, bl, acc[0][j], 0, 0, 0);
                acc[1][j] = __builtin_amdgcn_mfma_f32_16x16x32_f16(ah1, bl, acc[1][j], 0, 0, 0);
                acc[0][j] = __builtin_amdgcn_mfma_f32_16x16x32_f16(al0, bh, acc[0][j], 0, 0, 0);
                acc[1][j] = __builtin_amdgcn_mfma_f32_16x16x32_f16(al1, bh, acc[1][j], 0, 0, 0);
            }
        }
    }

    // ---- epilogue: C/D layout col=lane&15, row=(lane>>4)*4+reg (m89/m91)
    float* P = ks ? P1 : P0;
#pragma unroll
    for (int i = 0; i < 2; ++i) {
        const int row = m0 + wr * 32 + i * 16 + lkq * 4;
#pragma unroll
        for (int j = 0; j < 4; ++j) {
            const int col = n0 + wc * 64 + j * 16 + lrow;
#pragma unroll
            for (int r = 0; r < 4; ++r)
                P[(size_t)(row + r) * N + col] = acc[i][j][r];
        }
    }
}

// ---------------------------------------------------------------------------
// Kernel 2: gate. s = sigmoid(P0+P1+bias); group-limited top-8; renormalize.
// One wave per row; lane l owns experts 4l..4l+3. Stable ties (lower index).
// ---------------------------------------------------------------------------
__global__ __launch_bounds__(256) void gate_topk(
        const float* __restrict__ P0, const float* __restrict__ P1,
        const float* __restrict__ bias,
        float* __restrict__ out_w, float* __restrict__ out_i) {
    const int row = blockIdx.x * 4 + (threadIdx.x >> 6);
    const int lane = threadIdx.x & 63;

    const float4 a4 = *reinterpret_cast<const float4*>(P0 + (size_t)row * N + lane * 4);
    const float4 b4 = *reinterpret_cast<const float4*>(P1 + (size_t)row * N + lane * 4);
    const float4 bb = *reinterpret_cast<const float4*>(bias + lane * 4);
    float v[4] = {1.f / (1.f + expf(-(a4.x + b4.x + bb.x))),
                  1.f / (1.f + expf(-(a4.y + b4.y + bb.y))),
                  1.f / (1.f + expf(-(a4.z + b4.z + bb.z))),
                  1.f / (1.f + expf(-(a4.w + b4.w + bb.w)))};

    // per-lane top-2 (values) for the group score
    float t1 = v[0], t2 = -1.f;
#pragma unroll
    for (int j = 1; j < 4; ++j) {
        if (v[j] > t1) { t2 = t1; t1 = v[j]; }
        else if (v[j] > t2) { t2 = v[j]; }
    }
#pragma unroll
    for (int m = 1; m <= 4; m <<= 1) {
        const float o1 = __shfl_xor(t1, m, 64);
        const float o2 = __shfl_xor(t2, m, 64);
        const float n1 = fmaxf(t1, o1);
        const float n2 = fmaxf(fminf(t1, o1), fmaxf(t2, o2));
        t1 = n1; t2 = n2;
    }
    float gs = t1 + t2;
    int gid = lane >> 3;
#pragma unroll
    for (int m = 8; m <= 32; m <<= 1) {
        const float og = __shfl_xor(gs, m, 64);
        const int oi = __shfl_xor(gid, m, 64);
        if (og > gs || (og == gs && oi < gid)) { gs = og; gid = oi; }
    }

    const bool inG = ((lane >> 3) == gid);
    if (!inG) { v[0] = v[1] = v[2] = v[3] = -1.f; }

    float wv[8];
    int wi[8];
#pragma unroll
    for (int r = 0; r < 8; ++r) {
        float bv = v[0]; int bj = 0;
#pragma unroll
        for (int j = 1; j < 4; ++j)
            if (v[j] > bv) { bv = v[j]; bj = j; }
        int be = lane * 4 + bj;
#pragma unroll
        for (int m = 1; m <= 32; m <<= 1) {
            const float ov = __shfl_xor(bv, m, 64);
            const int oe = __shfl_xor(be, m, 64);
            if (ov > bv || (ov == bv && oe < be)) { bv = ov; be = oe; }
        }
        wv[r] = bv; wi[r] = be;
        if ((be >> 2) == lane) v[be & 3] = -1.f;
    }

    float sum = 0.f;
#pragma unroll
    for (int r = 0; r < 8; ++r) sum += wv[r];

    if (lane == 0) {
#pragma unroll
        for (int r = 0; r < 8; ++r) {
            out_w[(size_t)row * TOPK + r] = wv[r] / sum * ROUTE_SCALE;
            out_i[(size_t)row * TOPK + r] = (float)wi[r];
        }
    }
}

// ---------------------------------------------------------------------------
extern "C" void kernel_launch(void* const* d_in, const int* in_sizes, int n_in,
                              void* d_out, int out_size, void* d_ws, size_t ws_size,
                              hipStream_t stream) {
    const float* x = (const float*)d_in[0];   // [M,K]
    const float* w = (const float*)d_in[1];   // [N,K]
    const float* b = (const float*)d_in[2];   // [N]

    // ws layout (23.4 MB): Wh | Wl | P0 | P1
    char* ws = (char*)d_ws;
    _Float16* Wh = (_Float16*)ws;                              // 3,670,016 B
    _Float16* Wl = (_Float16*)(ws + 3670016);                  // 3,670,016 B
    float* P0 = (float*)(ws + 7340032);                        // 8,388,608 B
    float* P1 = (float*)(ws + 7340032 + 8388608);              // 8,388,608 B

    float* out_w = (float*)d_out;
    float* out_i = out_w + (size_t)M * TOPK;

    convert_w<<<(N * K / 4) / 256, 256, 0, stream>>>(w, Wh, Wl);
    gemm_split<<<512, 256, 0, stream>>>(x, Wh, Wl, P0, P1);
    gate_topk<<<M / 4, 256, 0, stream>>>(P0, P1, b, out_w, out_i);
}